// Round 15
// baseline (305.972 us; speedup 1.0000x reference)
//
#include <hip/hip_runtime.h>

// Problem constants (from reference setup_inputs)
#define NATOMS 32768
#define NFEAT 1920
#define HIDDEN 256
#define NSPEC 4
#define NSTRUCT 512
#define BK 32
#define MT 516                   // 64-row m-tiles (4 species padded to x64)
#define MPAD (MT * 64)           // 33024
#define KC 960                   // layer-1 K-chunk (KS=2)
#define NT1 (KC / BK)            // 30 steps
#define NBLK1 (MT * 2)           // 1032 layer-1 blocks (mt, kc)
#define NBLK2 (MT * 2)           // 1032 layer-2/3 blocks (mt, n-half)

typedef __bf16 bf16x8 __attribute__((ext_vector_type(8)));
typedef float f32x4 __attribute__((ext_vector_type(4)));
typedef float f32x8v __attribute__((ext_vector_type(8)));
typedef float f4v __attribute__((ext_vector_type(4)));
typedef unsigned short us4 __attribute__((ext_vector_type(4)));
typedef unsigned short us8 __attribute__((ext_vector_type(8)));

// Workspace layout (bytes). W2t/W3t alias W1t (tiled AFTER layer 1).
#define WS_INTS 0
#define WS_PERM 256
#define WS_W1T (WS_PERM + MPAD * 4)
#define WS_W2T WS_W1T                                    // alias (post-L1)
#define WS_W3T (WS_W2T + NSPEC * HIDDEN * HIDDEN * 2)
#define WS_W4T (WS_W1T + NSPEC * HIDDEN * NFEAT * 2)
#define WS_H1  (WS_W4T + 4096)
#define WS_H2  (WS_H1 + (size_t)MPAD * HIDDEN * 2)
#define WS_HP0 (WS_H2 + (size_t)MPAD * HIDDEN * 2)       // bf16 L1 partial (kc=0)
#define WS_HP1 (WS_HP0 + (size_t)MPAD * HIDDEN * 2)      // bf16 L1 partial (kc=1)
#define WS_END (WS_HP1 + (size_t)MPAD * HIDDEN * 2)      // ~72 MB

__device__ __forceinline__ unsigned short f2bf(float f) {
  unsigned int u = __float_as_uint(f);
  u += 0x7fffu + ((u >> 16) & 1u);           // round-to-nearest-even
  return (unsigned short)(u >> 16);
}
__device__ __forceinline__ float bf2f(unsigned short s) {
  return __uint_as_float(((unsigned int)s) << 16);
}
__device__ __forceinline__ float silu_n(float x) {
  return (x / (1.f + __expf(-x))) * 1.6765f; // variance-preserving SiLU
}

// Direct global->LDS async copy, 16 B per lane (CONTIGUOUS sources only).
__device__ __forceinline__ void gll16(const void* g, void* l) {
  __builtin_amdgcn_global_load_lds(
      (const __attribute__((address_space(1))) void*)g,
      (__attribute__((address_space(3))) void*)l, 16, 0, 0);
}

// ---- prep kernels -------------------------------------------------------

__global__ void k_init(int* ints, int* perm, float* out) {
  int i = blockIdx.x * blockDim.x + threadIdx.x;
  if (i < MPAD) perm[i] = -1;
  if (i < NSTRUCT) out[i] = 0.f;
  if (i < 8) ints[i] = 0;
}

__global__ void k_count(const int* __restrict__ species, int* counts) {
  __shared__ int c[NSPEC];
  int tid = threadIdx.x;
  if (tid < NSPEC) c[tid] = 0;
  __syncthreads();
  int s = species[blockIdx.x * 256 + tid];
  int lane = tid & 63;
#pragma unroll
  for (int sp = 0; sp < NSPEC; ++sp) {
    unsigned long long m = __ballot(s == sp);
    if (lane == 0 && m) atomicAdd(&c[sp], __popcll(m));
  }
  __syncthreads();
  if (tid < NSPEC && c[tid]) atomicAdd(&counts[tid], c[tid]);
}

__global__ void k_offsets(int* ints) {
  int* counts = ints;
  int* cursors = ints + 4;
  int* off = ints + 8;
  off[0] = 0;
  for (int s = 0; s < NSPEC; ++s) {
    off[s + 1] = off[s] + ((counts[s] + 63) & ~63);    // pad to 64
    cursors[s] = off[s];
  }
}

__global__ void k_scatter(const int* __restrict__ species, int* ints, int* perm) {
  __shared__ int cnt[4][NSPEC];
  __shared__ int base[NSPEC];
  int tid = threadIdx.x;
  int w = tid >> 6, lane = tid & 63;
  int i = blockIdx.x * 256 + tid;
  int s = species[i];
  unsigned long long m0 = __ballot(s == 0);
  unsigned long long m1 = __ballot(s == 1);
  unsigned long long m2 = __ballot(s == 2);
  unsigned long long m3 = __ballot(s == 3);
  if (lane == 0) {
    cnt[w][0] = __popcll(m0);
    cnt[w][1] = __popcll(m1);
    cnt[w][2] = __popcll(m2);
    cnt[w][3] = __popcll(m3);
  }
  __syncthreads();
  if (tid < NSPEC) {
    int t = cnt[0][tid] + cnt[1][tid] + cnt[2][tid] + cnt[3][tid];
    base[tid] = t ? atomicAdd(&ints[4 + tid], t) : 0;
  }
  __syncthreads();
  unsigned long long mm = (s == 0) ? m0 : (s == 1) ? m1 : (s == 2) ? m2 : m3;
  int pos = base[s] + __popcll(mm & ((1ull << lane) - 1ull));
#pragma unroll
  for (int ww = 0; ww < 4; ++ww)
    if (ww < w) pos += cnt[ww][s];
  perm[pos] = i;
}

// f32 [S][K][N=256] -> bf16 TILED STAGING LAYOUT (proven R13):
// Wt[sp][t=k/32][chunk=n/16][lane][8 shorts], lane=(n&15)*4|(kgran^((n>>2)&3)).
__global__ void k_wtile(const float* __restrict__ src, unsigned short* __restrict__ dst,
                        int K, int N) {
  __shared__ unsigned short T[64][72];
  int ntN = N >> 6, ntK = K >> 6;
  int per = ntK * ntN;
  int b = blockIdx.x;
  int s = b / per, rem = b % per;
  int k0 = (rem / ntN) << 6;
  int n0 = (rem % ntN) << 6;
  int tid = threadIdx.x;
  int r = tid >> 2, cb = (tid & 3) << 4;
  const float* p = src + ((size_t)s * K + k0 + r) * N + n0 + cb;
#pragma unroll
  for (int j = 0; j < 16; j += 4) {
    f4v v = *(const f4v*)(p + j);
#pragma unroll
    for (int e = 0; e < 4; ++e) T[r][cb + j + e] = f2bf(v[e]);   // T[k-local][n-local]
  }
  __syncthreads();
  unsigned short* base = dst + (size_t)s * HIDDEN * K;
  int row_n = n0 + r;
#pragma unroll
  for (int g2 = 0; g2 < 2; ++g2) {
    int kl = cb + g2 * 8;
    int kg = k0 + kl;
    int t = kg >> 5;
    int kgl = (kg >> 3) & 3;
    int lanepos = ((row_n & 15) << 2) | (kgl ^ ((row_n >> 2) & 3));
    unsigned short v[8];
#pragma unroll
    for (int e = 0; e < 8; ++e) v[e] = T[kl + e][r];
    uint4 u;
    u.x = v[0] | ((unsigned)v[1] << 16);
    u.y = v[2] | ((unsigned)v[3] << 16);
    u.z = v[4] | ((unsigned)v[5] << 16);
    u.w = v[6] | ((unsigned)v[7] << 16);
    *(uint4*)(base + (size_t)t * 8192 + ((row_n >> 4) << 9) + lanepos * 8) = u;
  }
}

__global__ void k_w4(const float* __restrict__ src, unsigned short* __restrict__ dst) {
  int i = blockIdx.x * 256 + threadIdx.x;
  dst[i] = f2bf(src[i]);
}

// ---- layer 1: direct-from-global A fragments, B tiled gll16 -------------
// No scattered LDS-DMA anywhere: A-fragments (8 consecutive k of one gathered
// row) are loaded with NORMAL per-lane vector loads straight into registers
// (double-buffered, 1-step prefetch) and converted via v_cvt_pk_bf16_f32 at
// use. B streams through LDS with contiguous-source gll16 (R13-proven tiled
// layout). BM=64 x BN=256, KS=2 (A touches HBM exactly once), grid 1032.
// Each kc writes its bf16 partial buffer (plain stores, no atomics).
__global__ __launch_bounds__(256) void k_l1d(
    const float* __restrict__ xf, const unsigned short* __restrict__ Wt,
    unsigned short* __restrict__ Hp0, unsigned short* __restrict__ Hp1,
    const int* __restrict__ perm, const int* __restrict__ off, float scale) {
  __shared__ __align__(16) unsigned short Bsl[2 * 8192];  // 2 x 16 KB (bf16 256x32)
  unsigned short* bl = Bsl;

  // XCD-chunked bijective swizzle: both kc of one mt land adjacent (same XCD)
  int nwg = gridDim.x;
  int xcd = blockIdx.x & 7, idx = blockIdx.x >> 3;
  int q = nwg >> 3, r = nwg & 7;
  int lb = (xcd < r ? xcd * (q + 1) : r * (q + 1) + (xcd - r) * q) + idx;
  int mt = lb >> 1, kc = lb & 1;

  int rowbase = mt * 64;
  int kbase = kc * KC;
  int tid = threadIdx.x;
  int wc = tid >> 6, lane = tid & 63;      // 4 waves = 4 col-blocks of 64
  int lr = lane & 15, lg = lane >> 4;

  int sp;
  if (rowbase < off[1]) sp = 0;
  else if (rowbase < off[2]) sp = 1;
  else if (rowbase < off[3]) sp = 2;
  else sp = 3;

  // per-thread A row pointers (4 rows: m*16+lr), safe fallback for pads
  const float* rp[4];
  bool val[4];
#pragma unroll
  for (int m = 0; m < 4; ++m) {
    long as = perm[rowbase + m * 16 + lr];
    val[m] = (as >= 0);
    rp[m] = xf + (val[m] ? (size_t)as * NFEAT : 0) + kbase + lg * 8;
  }

  // B: tiled layout, kc's 30 t-blocks; 4 contiguous gll16 per thread per step
  const unsigned short* wsp = Wt + (size_t)sp * HIDDEN * NFEAT + (size_t)(kc * NT1) * 8192;
  auto STAGEB = [&](int b, int t) {
#pragma unroll
    for (int qq = 0; qq < 4; ++qq)
      gll16(wsp + (size_t)t * 8192 + qq * 2048 + tid * 8,
            bl + b * 8192 + qq * 2048 + tid * 8);
  };

  f32x4 zero4 = {0.f, 0.f, 0.f, 0.f};
  f32x4 acc[4][4];
#pragma unroll
  for (int m = 0; m < 4; ++m)
#pragma unroll
    for (int n = 0; n < 4; ++n) acc[m][n] = zero4;

  auto LOADF = [&](int t, f32x8v (&fr)[4]) {
#pragma unroll
    for (int m = 0; m < 4; ++m) fr[m] = *(const f32x8v*)(rp[m] + t * 32);
  };

  int buf = 0;
  auto BODY = [&](int t, f32x8v (&cur)[4], f32x8v (&nxt)[4]) {
    if (t + 1 < NT1) {
      STAGEB(buf ^ 1, t + 1);
      LOADF(t + 1, nxt);
    }
    bf16x8 a[4], b[4];
#pragma unroll
    for (int m = 0; m < 4; ++m) {
      unsigned r01, r23, r45, r67;
      asm("v_cvt_pk_bf16_f32 %0, %1, %2" : "=v"(r01) : "v"(cur[m][0]), "v"(cur[m][1]));
      asm("v_cvt_pk_bf16_f32 %0, %1, %2" : "=v"(r23) : "v"(cur[m][2]), "v"(cur[m][3]));
      asm("v_cvt_pk_bf16_f32 %0, %1, %2" : "=v"(r45) : "v"(cur[m][4]), "v"(cur[m][5]));
      asm("v_cvt_pk_bf16_f32 %0, %1, %2" : "=v"(r67) : "v"(cur[m][6]), "v"(cur[m][7]));
      union { unsigned u[4]; bf16x8 v; } cv = {{r01, r23, r45, r67}};
      union { unsigned u[4]; bf16x8 v; } zu = {{0, 0, 0, 0}};
      a[m] = val[m] ? cv.v : zu.v;
    }
#pragma unroll
    for (int n = 0; n < 4; ++n) {
      int row = wc * 64 + n * 16 + lr;
      b[n] = *(const bf16x8*)(bl + buf * 8192 + row * 32 +
                              ((lg ^ ((row >> 2) & 3)) << 3));
    }
#pragma unroll
    for (int m = 0; m < 4; ++m)
#pragma unroll
      for (int n = 0; n < 4; ++n)
        acc[m][n] = __builtin_amdgcn_mfma_f32_16x16x32_bf16(a[m], b[n], acc[m][n], 0, 0, 0);
    __syncthreads();
    buf ^= 1;
  };

  f32x8v fA[4], fB[4];
  STAGEB(0, 0);
  LOADF(0, fA);
  __syncthreads();                         // B(0) in LDS (vmcnt drain)
  for (int t2 = 0; t2 < NT1 / 2; ++t2) {
    BODY(2 * t2, fA, fB);
    BODY(2 * t2 + 1, fB, fA);
  }

  // epilogue: bf16 partial (scale only; silu deferred to layer 2)
  unsigned short* Hp = kc ? Hp1 : Hp0;
#pragma unroll
  for (int m = 0; m < 4; ++m)
#pragma unroll
    for (int n = 0; n < 4; ++n)
#pragma unroll
      for (int rr = 0; rr < 4; ++rr)
        Hp[(size_t)(rowbase + m * 16 + lg * 4 + rr) * HIDDEN +
           wc * 64 + n * 16 + lr] = f2bf(acc[m][n][rr] * scale);
}

// ---- layer 2: A = silu(Hp0+Hp1), fragments direct from global -----------
__global__ __launch_bounds__(256) void k_mlp2s(
    const unsigned short* __restrict__ hp0, const unsigned short* __restrict__ hp1,
    const unsigned short* __restrict__ Wt, unsigned short* __restrict__ Hout,
    const int* __restrict__ off, float scale) {
  constexpr int K = HIDDEN;
  __shared__ __align__(16) unsigned short Bsl[2 * 4096];  // 2 x 8 KB (128x32)
  unsigned short* bl = Bsl;

  int nwg = gridDim.x;
  int xcd = blockIdx.x & 7, idx = blockIdx.x >> 3;
  int q = nwg >> 3, r = nwg & 7;
  int lb = (xcd < r ? xcd * (q + 1) : r * (q + 1) + (xcd - r) * q) + idx;
  int mt = lb >> 1, bn = lb & 1;

  int rowbase = mt * 64;
  int tid = threadIdx.x;
  int w = tid >> 6, lane = tid & 63;
  int wr = w >> 1, wc = w & 1;
  int lr = lane & 15, lg = lane >> 4;

  int sp;
  if (rowbase < off[1]) sp = 0;
  else if (rowbase < off[2]) sp = 1;
  else if (rowbase < off[3]) sp = 2;
  else sp = 3;

  // B: tiled contiguous chunks
  const unsigned short* srcB[2];
  int ldsB[2];
#pragma unroll
  for (int qq = 0; qq < 2; ++qq) {
    int gc = bn * 8 + w * 2 + qq;
    srcB[qq] = Wt + (size_t)sp * HIDDEN * K + gc * 512 + lane * 8;
    ldsB[qq] = (w * 2 + qq) * 512;
  }
  // A: direct per-lane loads from Hp rows
  const unsigned short* ra0[2];
  const unsigned short* ra1[2];
#pragma unroll
  for (int m = 0; m < 2; ++m) {
    size_t row = (size_t)(rowbase + wr * 32 + m * 16 + lr);
    ra0[m] = hp0 + row * K + lg * 8;
    ra1[m] = hp1 + row * K + lg * 8;
  }

  auto STAGE = [&](int b, int t) {
#pragma unroll
    for (int qq = 0; qq < 2; ++qq)
      gll16(srcB[qq] + (size_t)t * 8192, bl + b * 4096 + ldsB[qq]);
  };

  f32x4 zero4 = {0.f, 0.f, 0.f, 0.f};
  f32x4 acc[2][4];
#pragma unroll
  for (int m = 0; m < 2; ++m)
#pragma unroll
    for (int n = 0; n < 4; ++n) acc[m][n] = zero4;

  constexpr int NT = K / BK;
  STAGE(0, 0);
  __syncthreads();
  int buf = 0;
  for (int t = 0; t < NT; ++t) {
    if (t + 1 < NT) STAGE(buf ^ 1, t + 1);

    bf16x8 a[2], b[4];
#pragma unroll
    for (int m = 0; m < 2; ++m) {
      us8 h0 = *(const us8*)(ra0[m] + t * BK);
      us8 h1 = *(const us8*)(ra1[m] + t * BK);
      union { unsigned short u[8]; bf16x8 v; } cv;
#pragma unroll
      for (int e = 0; e < 8; ++e)
        cv.u[e] = f2bf(silu_n(bf2f(h0[e]) + bf2f(h1[e])));
      a[m] = cv.v;
    }
#pragma unroll
    for (int n = 0; n < 4; ++n) {
      int row = wc * 64 + n * 16 + lr;
      b[n] = *(const bf16x8*)(bl + buf * 4096 + row * 32 +
                              ((lg ^ ((row >> 2) & 3)) << 3));
    }
#pragma unroll
    for (int m = 0; m < 2; ++m)
#pragma unroll
      for (int n = 0; n < 4; ++n)
        acc[m][n] = __builtin_amdgcn_mfma_f32_16x16x32_bf16(a[m], b[n], acc[m][n], 0, 0, 0);

    __syncthreads();
    buf ^= 1;
  }

#pragma unroll
  for (int m = 0; m < 2; ++m)
#pragma unroll
    for (int n = 0; n < 4; ++n)
#pragma unroll
      for (int rr = 0; rr < 4; ++rr) {
        float v = acc[m][n][rr] * scale;
        Hout[(size_t)(rowbase + wr * 32 + m * 16 + lg * 4 + rr) * HIDDEN +
             bn * 128 + wc * 64 + n * 16 + lr] = f2bf(silu_n(v));
      }
}

// ---- layer 3: A = bf16 fragments direct from global ---------------------
__global__ __launch_bounds__(256) void k_mlp3(
    const unsigned short* __restrict__ xb, const unsigned short* __restrict__ Wt,
    unsigned short* __restrict__ Hout, const int* __restrict__ off, float scale) {
  constexpr int K = HIDDEN;
  __shared__ __align__(16) unsigned short Bsl[2 * 4096];
  unsigned short* bl = Bsl;

  int nwg = gridDim.x;
  int xcd = blockIdx.x & 7, idx = blockIdx.x >> 3;
  int q = nwg >> 3, r = nwg & 7;
  int lb = (xcd < r ? xcd * (q + 1) : r * (q + 1) + (xcd - r) * q) + idx;
  int mt = lb >> 1, bn = lb & 1;

  int rowbase = mt * 64;
  int tid = threadIdx.x;
  int w = tid >> 6, lane = tid & 63;
  int wr = w >> 1, wc = w & 1;
  int lr = lane & 15, lg = lane >> 4;

  int sp;
  if (rowbase < off[1]) sp = 0;
  else if (rowbase < off[2]) sp = 1;
  else if (rowbase < off[3]) sp = 2;
  else sp = 3;

  const unsigned short* srcB[2];
  int ldsB[2];
#pragma unroll
  for (int qq = 0; qq < 2; ++qq) {
    int gc = bn * 8 + w * 2 + qq;
    srcB[qq] = Wt + (size_t)sp * HIDDEN * K + gc * 512 + lane * 8;
    ldsB[qq] = (w * 2 + qq) * 512;
  }
  const unsigned short* ra[2];
#pragma unroll
  for (int m = 0; m < 2; ++m) {
    size_t row = (size_t)(rowbase + wr * 32 + m * 16 + lr);
    ra[m] = xb + row * K + lg * 8;
  }

  auto STAGE = [&](int b, int t) {
#pragma unroll
    for (int qq = 0; qq < 2; ++qq)
      gll16(srcB[qq] + (size_t)t * 8192, bl + b * 4096 + ldsB[qq]);
  };

  f32x4 zero4 = {0.f, 0.f, 0.f, 0.f};
  f32x4 acc[2][4];
#pragma unroll
  for (int m = 0; m < 2; ++m)
#pragma unroll
    for (int n = 0; n < 4; ++n) acc[m][n] = zero4;

  constexpr int NT = K / BK;
  STAGE(0, 0);
  __syncthreads();
  int buf = 0;
  for (int t = 0; t < NT; ++t) {
    if (t + 1 < NT) STAGE(buf ^ 1, t + 1);

    bf16x8 a[2], b[4];
#pragma unroll
    for (int m = 0; m < 2; ++m)
      a[m] = *(const bf16x8*)(ra[m] + t * BK);
#pragma unroll
    for (int n = 0; n < 4; ++n) {
      int row = wc * 64 + n * 16 + lr;
      b[n] = *(const bf16x8*)(bl + buf * 4096 + row * 32 +
                              ((lg ^ ((row >> 2) & 3)) << 3));
    }
#pragma unroll
    for (int m = 0; m < 2; ++m)
#pragma unroll
      for (int n = 0; n < 4; ++n)
        acc[m][n] = __builtin_amdgcn_mfma_f32_16x16x32_bf16(a[m], b[n], acc[m][n], 0, 0, 0);

    __syncthreads();
    buf ^= 1;
  }

#pragma unroll
  for (int m = 0; m < 2; ++m)
#pragma unroll
    for (int n = 0; n < 4; ++n)
#pragma unroll
      for (int rr = 0; rr < 4; ++rr) {
        float v = acc[m][n][rr] * scale;
        Hout[(size_t)(rowbase + wr * 32 + m * 16 + lg * 4 + rr) * HIDDEN +
             bn * 128 + wc * 64 + n * 16 + lr] = f2bf(silu_n(v));
      }
}

// ---- layer 4 + segment reduction ---------------------------------------
__global__ void k_l4(const unsigned short* __restrict__ H3, const unsigned short* __restrict__ W4t,
                     const int* __restrict__ perm, const int* __restrict__ species,
                     const int* __restrict__ sidx, const float* __restrict__ coeff,
                     float* __restrict__ out) {
  int w = threadIdx.x >> 6, l = threadIdx.x & 63;
  int row = blockIdx.x * 4 + w;
  int src = perm[row];
  if (src < 0) return;
  int sp = species[src];
  us4 h = *(const us4*)&H3[(size_t)row * HIDDEN + l * 4];
  us4 wv = *(const us4*)&W4t[sp * HIDDEN + l * 4];
  float sum = 0.f;
#pragma unroll
  for (int e = 0; e < 4; ++e) sum += bf2f(h[e]) * bf2f(wv[e]);
#pragma unroll
  for (int d = 32; d >= 1; d >>= 1) sum += __shfl_xor(sum, d, 64);
  if (l == 0)
    atomicAdd(&out[sidx[src]], sum * (0.0625f * 0.125f) + coeff[sp]);
}

// ---- launcher -----------------------------------------------------------
extern "C" void kernel_launch(void* const* d_in, const int* in_sizes, int n_in,
                              void* d_out, int out_size, void* d_ws, size_t ws_size,
                              hipStream_t stream) {
  const float* features = (const float*)d_in[0];
  const float* W1 = (const float*)d_in[1];
  const float* W2 = (const float*)d_in[2];
  const float* W3 = (const float*)d_in[3];
  const float* W4 = (const float*)d_in[4];
  const float* coeff = (const float*)d_in[5];
  const int* species = (const int*)d_in[6];
  const int* sidx = (const int*)d_in[7];
  float* out = (float*)d_out;

  char* ws = (char*)d_ws;
  int* ints = (int*)(ws + WS_INTS);
  int* perm = (int*)(ws + WS_PERM);
  unsigned short* W1t = (unsigned short*)(ws + WS_W1T);
  unsigned short* W2t = (unsigned short*)(ws + WS_W2T);
  unsigned short* W3t = (unsigned short*)(ws + WS_W3T);
  unsigned short* W4t = (unsigned short*)(ws + WS_W4T);
  unsigned short* H1 = (unsigned short*)(ws + WS_H1);
  unsigned short* H2 = (unsigned short*)(ws + WS_H2);
  unsigned short* Hp0 = (unsigned short*)(ws + WS_HP0);
  unsigned short* Hp1 = (unsigned short*)(ws + WS_HP1);

  // species bucketing
  k_init<<<(MPAD + 255) / 256, 256, 0, stream>>>(ints, perm, out);
  k_count<<<NATOMS / 256, 256, 0, stream>>>(species, ints);
  k_offsets<<<1, 1, 0, stream>>>(ints);
  k_scatter<<<NATOMS / 256, 256, 0, stream>>>(species, ints, perm);

  // weight prep for layer 1 (W2/W3 tiled after L1 — they alias W1t)
  k_wtile<<<NSPEC * (NFEAT / 64) * (HIDDEN / 64), 256, 0, stream>>>(W1, W1t, NFEAT, HIDDEN);
  k_w4<<<NSPEC, 256, 0, stream>>>(W4, W4t);

  const float s1 = 1.f / sqrtf((float)NFEAT);
  const float s2 = 1.f / 16.f;

  // layer 1: direct-A fragments, KS=2, bf16 partials
  k_l1d<<<NBLK1, 256, 0, stream>>>(features, W1t, Hp0, Hp1, perm, ints + 8, s1);

  // W2/W3 prep (W1t region now dead)
  k_wtile<<<NSPEC * (HIDDEN / 64) * (HIDDEN / 64), 256, 0, stream>>>(W2, W2t, HIDDEN, HIDDEN);
  k_wtile<<<NSPEC * (HIDDEN / 64) * (HIDDEN / 64), 256, 0, stream>>>(W3, W3t, HIDDEN, HIDDEN);

  // layer 2 (sum partials + silu at A-load), layer 3
  k_mlp2s<<<NBLK2, 256, 0, stream>>>(Hp0, Hp1, W2t, H2, ints + 8, s2);
  k_mlp3<<<NBLK2, 256, 0, stream>>>(H2, W3t, H1, ints + 8, s2);

  // layer 4 + segment sum + composition term
  k_l4<<<MPAD / 4, 256, 0, stream>>>(H1, W4t, perm, species, sidx, coeff, out);
}

// Round 16
// 169.031 us; speedup vs baseline: 1.8102x; 1.8102x over previous
//
#include <hip/hip_runtime.h>

// Problem constants (from reference setup_inputs)
#define NATOMS 32768
#define NFEAT 1920
#define HIDDEN 256
#define NSPEC 4
#define NSTRUCT 512
#define BK 32
#define MT128 260                // 128-row m-tiles (4 species padded to x128)
#define MPAD (MT128 * 128)       // 33280
#define NT1 (NFEAT / BK)         // 60 K-steps (full K, no split)
#define NBLK1 (MT128 * 2)        // 520 layer-1 blocks (mt, n-half)
#define NBLK2 ((MPAD / 64) * 2)  // 1040 layer-2/3 blocks (64-row tile, n-half)

typedef __bf16 bf16x8 __attribute__((ext_vector_type(8)));
typedef float f32x4 __attribute__((ext_vector_type(4)));
typedef float f4v __attribute__((ext_vector_type(4)));
typedef unsigned short us4 __attribute__((ext_vector_type(4)));

// Workspace layout (bytes). W2t/W3t alias W1t (tiled AFTER layer 1).
#define WS_INTS 0                                        // ints[0..3] counts,[4..7] cursors,[8..12] off; bytes 128..191 zero-stub
#define WS_PERM 256
#define WS_W1T (WS_PERM + MPAD * 4)
#define WS_W2T WS_W1T                                    // alias (post-L1)
#define WS_W3T (WS_W2T + NSPEC * HIDDEN * HIDDEN * 2)
#define WS_W4T (WS_W1T + NSPEC * HIDDEN * NFEAT * 2)
#define WS_H1  (WS_W4T + 4096)
#define WS_H2  (WS_H1 + (size_t)MPAD * HIDDEN * 2)       // end ~38 MB

__device__ __forceinline__ unsigned short f2bf(float f) {
  unsigned int u = __float_as_uint(f);
  u += 0x7fffu + ((u >> 16) & 1u);           // round-to-nearest-even
  return (unsigned short)(u >> 16);
}
__device__ __forceinline__ float bf2f(unsigned short s) {
  return __uint_as_float(((unsigned int)s) << 16);
}
__device__ __forceinline__ float silu_n(float x) {
  return (x / (1.f + __expf(-x))) * 1.6765f; // variance-preserving SiLU
}

// Direct global->LDS async copy, 16 B per lane. LDS dest = wave-uniform base.
__device__ __forceinline__ void gll16(const void* g, void* l) {
  __builtin_amdgcn_global_load_lds(
      (const __attribute__((address_space(1))) void*)g,
      (__attribute__((address_space(3))) void*)l, 16, 0, 0);
}

// ---- prep kernels -------------------------------------------------------

__global__ void k_init(int* ints, int* perm, float* out) {
  int i = blockIdx.x * blockDim.x + threadIdx.x;
  if (i < MPAD) perm[i] = -1;
  if (i < NSTRUCT) out[i] = 0.f;
  if (i < 8) ints[i] = 0;
  if (i >= 32 && i < 48) ((float*)ints)[i] = 0.f;   // zero-stub for padded gather rows
}

__global__ void k_count(const int* __restrict__ species, int* counts) {
  __shared__ int c[NSPEC];
  int tid = threadIdx.x;
  if (tid < NSPEC) c[tid] = 0;
  __syncthreads();
  int s = species[blockIdx.x * 256 + tid];
  int lane = tid & 63;
#pragma unroll
  for (int sp = 0; sp < NSPEC; ++sp) {
    unsigned long long m = __ballot(s == sp);
    if (lane == 0 && m) atomicAdd(&c[sp], __popcll(m));
  }
  __syncthreads();
  if (tid < NSPEC && c[tid]) atomicAdd(&counts[tid], c[tid]);
}

__global__ void k_offsets(int* ints) {
  int* counts = ints;
  int* cursors = ints + 4;
  int* off = ints + 8;
  off[0] = 0;
  for (int s = 0; s < NSPEC; ++s) {
    off[s + 1] = off[s] + ((counts[s] + 127) & ~127);   // pad to 128 (L1 BM)
    cursors[s] = off[s];
  }
}

__global__ void k_scatter(const int* __restrict__ species, int* ints, int* perm) {
  __shared__ int cnt[4][NSPEC];
  __shared__ int base[NSPEC];
  int tid = threadIdx.x;
  int w = tid >> 6, lane = tid & 63;
  int i = blockIdx.x * 256 + tid;
  int s = species[i];
  unsigned long long m0 = __ballot(s == 0);
  unsigned long long m1 = __ballot(s == 1);
  unsigned long long m2 = __ballot(s == 2);
  unsigned long long m3 = __ballot(s == 3);
  if (lane == 0) {
    cnt[w][0] = __popcll(m0);
    cnt[w][1] = __popcll(m1);
    cnt[w][2] = __popcll(m2);
    cnt[w][3] = __popcll(m3);
  }
  __syncthreads();
  if (tid < NSPEC) {
    int t = cnt[0][tid] + cnt[1][tid] + cnt[2][tid] + cnt[3][tid];
    base[tid] = t ? atomicAdd(&ints[4 + tid], t) : 0;
  }
  __syncthreads();
  unsigned long long mm = (s == 0) ? m0 : (s == 1) ? m1 : (s == 2) ? m2 : m3;
  int pos = base[s] + __popcll(mm & ((1ull << lane) - 1ull));
#pragma unroll
  for (int ww = 0; ww < 4; ++ww)
    if (ww < w) pos += cnt[ww][s];
  perm[pos] = i;
}

// f32 [S][K][N=256] -> bf16 TILED STAGING LAYOUT (proven R13):
// Wt[sp][t=k/32][chunk=n/16][lane][8 shorts], lane=(n&15)*4|(kgran^((n>>2)&3)).
// Consumer gll16s read contiguous 1-KB-aligned bursts; LDS image keeps the
// XOR bank swizzle.
__global__ void k_wtile(const float* __restrict__ src, unsigned short* __restrict__ dst,
                        int K, int N) {
  __shared__ unsigned short T[64][72];
  int ntN = N >> 6, ntK = K >> 6;
  int per = ntK * ntN;
  int b = blockIdx.x;
  int s = b / per, rem = b % per;
  int k0 = (rem / ntN) << 6;
  int n0 = (rem % ntN) << 6;
  int tid = threadIdx.x;
  int r = tid >> 2, cb = (tid & 3) << 4;
  const float* p = src + ((size_t)s * K + k0 + r) * N + n0 + cb;
#pragma unroll
  for (int j = 0; j < 16; j += 4) {
    f4v v = *(const f4v*)(p + j);
#pragma unroll
    for (int e = 0; e < 4; ++e) T[r][cb + j + e] = f2bf(v[e]);   // T[k-local][n-local]
  }
  __syncthreads();
  unsigned short* base = dst + (size_t)s * HIDDEN * K;
  int row_n = n0 + r;
#pragma unroll
  for (int g2 = 0; g2 < 2; ++g2) {
    int kl = cb + g2 * 8;
    int kg = k0 + kl;
    int t = kg >> 5;
    int kgl = (kg >> 3) & 3;
    int lanepos = ((row_n & 15) << 2) | (kgl ^ ((row_n >> 2) & 3));
    unsigned short v[8];
#pragma unroll
    for (int e = 0; e < 8; ++e) v[e] = T[kl + e][r];
    uint4 u;
    u.x = v[0] | ((unsigned)v[1] << 16);
    u.y = v[2] | ((unsigned)v[3] << 16);
    u.z = v[4] | ((unsigned)v[5] << 16);
    u.w = v[6] | ((unsigned)v[7] << 16);
    *(uint4*)(base + (size_t)t * 8192 + ((row_n >> 4) << 9) + lanepos * 8) = u;
  }
}

__global__ void k_w4(const float* __restrict__ src, unsigned short* __restrict__ dst) {
  int i = blockIdx.x * 256 + threadIdx.x;
  dst[i] = f2bf(src[i]);
}

// ---- layer 1: BM=128 x BN=128, full K, byte-reduced staging -------------
// Staged = A(f32, x2 n-halves) 507 MB + B(tiled contiguous, x260 m-tiles)
// 254 MB = 761 MB (vs R13's 1014 MB; validated cap ~6.5 TB/s).
// Grid 520 (2 residents/CU at 48 KB LDS, 512 thr = 8 waves as 4x2 of 32x64).
// No K-split, no partials: silu+bf16 direct to H1.
__global__ __launch_bounds__(512) void k_l1n(
    const float* __restrict__ xf, const unsigned short* __restrict__ Wt,
    unsigned short* __restrict__ Hout, const int* __restrict__ perm,
    const int* __restrict__ off, const float* __restrict__ zs, float scale) {
  __shared__ __align__(16) unsigned short Asl[2 * 8192];  // f32 128x32 dbuf (32 KB)
  __shared__ __align__(16) unsigned short Bsl[2 * 4096];  // bf16 128x32 dbuf (16 KB)
  float* af = (float*)Asl;
  unsigned short* bl = Bsl;

  // XCD-chunked bijective swizzle: both n-halves of one mt adjacent (same
  // XCD) -> shared A panel hits L2 on the second read.
  int nwg = gridDim.x;
  int xcd = blockIdx.x & 7, idx = blockIdx.x >> 3;
  int q = nwg >> 3, r = nwg & 7;
  int lb = (xcd < r ? xcd * (q + 1) : r * (q + 1) + (xcd - r) * q) + idx;
  int mt = lb >> 1, bn = lb & 1;

  int rowbase = mt * 128;
  int tid = threadIdx.x;
  int w = tid >> 6, lane = tid & 63;
  int wr = w >> 1, wc = w & 1;             // 8 waves: 4 row x 2 col of 32x64
  int lr = lane & 15, lg = lane >> 4;

  int sp;
  if (rowbase < off[1]) sp = 0;
  else if (rowbase < off[2]) sp = 1;
  else if (rowbase < off[3]) sp = 2;
  else sp = 3;

  // A (f32): 128 rows x 128 B = 16 chunks of 1 KB; wave w stages chunks
  // qq*8+w (qq=0,1); row = chunk*8 + (lane>>3); slot = (lane&7)^(row&7).
  const float* srcA[2];
  int ldsA[2];
#pragma unroll
  for (int qq = 0; qq < 2; ++qq) {
    int c = qq * 8 + w;
    int row = c * 8 + (lane >> 3);
    int slot = (lane & 7) ^ (row & 7);
    long as = perm[rowbase + row];
    srcA[qq] = (as >= 0) ? (xf + (size_t)as * NFEAT + slot * 4) : nullptr;
    ldsA[qq] = c * 256;                    // floats (wave-uniform base)
  }
  // B: tiled layout; bn-half of each 16-KB t-block is a contiguous 8 KB.
  const unsigned short* wsp =
      Wt + (size_t)sp * HIDDEN * NFEAT + (size_t)bn * 4096;

  auto STAGE = [&](int b, int t) {
#pragma unroll
    for (int qq = 0; qq < 2; ++qq) {
      const float* s = srcA[qq] ? srcA[qq] + t * BK : zs;
      gll16(s, af + b * 4096 + ldsA[qq]);
    }
    gll16(wsp + (size_t)t * 8192 + tid * 8, bl + b * 4096 + tid * 8);
  };

  f32x4 zero4 = {0.f, 0.f, 0.f, 0.f};
  f32x4 acc[2][4];
#pragma unroll
  for (int m = 0; m < 2; ++m)
#pragma unroll
    for (int n = 0; n < 4; ++n) acc[m][n] = zero4;

  STAGE(0, 0);
  __syncthreads();
  int buf = 0;
  for (int t = 0; t < NT1; ++t) {
    if (t + 1 < NT1) STAGE(buf ^ 1, t + 1);

    bf16x8 a[2], b[4];
#pragma unroll
    for (int m = 0; m < 2; ++m) {
      int row = wr * 32 + m * 16 + lr;
      const float* base = af + buf * 4096 + row * 32;
      f4v x0 = *(const f4v*)(base + (((lg << 1) ^ (row & 7)) << 2));
      f4v x1 = *(const f4v*)(base + ((((lg << 1) | 1) ^ (row & 7)) << 2));
      unsigned r01, r23, r45, r67;
      asm("v_cvt_pk_bf16_f32 %0, %1, %2" : "=v"(r01) : "v"(x0[0]), "v"(x0[1]));
      asm("v_cvt_pk_bf16_f32 %0, %1, %2" : "=v"(r23) : "v"(x0[2]), "v"(x0[3]));
      asm("v_cvt_pk_bf16_f32 %0, %1, %2" : "=v"(r45) : "v"(x1[0]), "v"(x1[1]));
      asm("v_cvt_pk_bf16_f32 %0, %1, %2" : "=v"(r67) : "v"(x1[2]), "v"(x1[3]));
      union { unsigned u[4]; bf16x8 v; } cv = {{r01, r23, r45, r67}};
      a[m] = cv.v;
    }
#pragma unroll
    for (int n = 0; n < 4; ++n) {
      int row = wc * 64 + n * 16 + lr;     // 0..127 local B row
      b[n] = *(const bf16x8*)(bl + buf * 4096 + row * 32 +
                              ((lg ^ ((row >> 2) & 3)) << 3));
    }
#pragma unroll
    for (int m = 0; m < 2; ++m)
#pragma unroll
      for (int n = 0; n < 4; ++n)
        acc[m][n] = __builtin_amdgcn_mfma_f32_16x16x32_bf16(a[m], b[n], acc[m][n], 0, 0, 0);

    __syncthreads();
    buf ^= 1;
  }

  // epilogue: silu + bf16 -> H1
#pragma unroll
  for (int m = 0; m < 2; ++m)
#pragma unroll
    for (int n = 0; n < 4; ++n)
#pragma unroll
      for (int rr = 0; rr < 4; ++rr) {
        float v = acc[m][n][rr] * scale;
        Hout[(size_t)(rowbase + wr * 32 + m * 16 + lg * 4 + rr) * HIDDEN +
             bn * 128 + wc * 64 + n * 16 + lr] = f2bf(silu_n(v));
      }
}

// ---- layers 2/3: BM=64 x BN=128, tiled-contiguous B (R13-proven) --------
__global__ __launch_bounds__(256) void k_mlp2(
    const unsigned short* __restrict__ xb, const unsigned short* __restrict__ Wt,
    unsigned short* __restrict__ Hout, const int* __restrict__ off, float scale) {
  constexpr int K = HIDDEN;
  __shared__ __align__(16) unsigned short Asl[2 * 2048];
  __shared__ __align__(16) unsigned short Bsl[2 * 4096];
  unsigned short* ab = Asl;
  unsigned short* bl = Bsl;

  int nwg = gridDim.x;
  int xcd = blockIdx.x & 7, idx = blockIdx.x >> 3;
  int q = nwg >> 3, r = nwg & 7;
  int lb = (xcd < r ? xcd * (q + 1) : r * (q + 1) + (xcd - r) * q) + idx;
  int mt = lb >> 1, bn = lb & 1;

  int rowbase = mt * 64;
  int tid = threadIdx.x;
  int w = tid >> 6, lane = tid & 63;
  int wr = w >> 1, wc = w & 1;
  int lr = lane & 15, lg = lane >> 4;

  int sp;
  if (rowbase < off[1]) sp = 0;
  else if (rowbase < off[2]) sp = 1;
  else if (rowbase < off[3]) sp = 2;
  else sp = 3;

  const unsigned short* srcB[2];
  int ldsB[2];
#pragma unroll
  for (int qq = 0; qq < 2; ++qq) {
    int gc = bn * 8 + w * 2 + qq;
    srcB[qq] = Wt + (size_t)sp * HIDDEN * K + gc * 512 + lane * 8;
    ldsB[qq] = (w * 2 + qq) * 512;
  }
  int arow = w * 16 + (lane >> 2);
  int aslot = (lane & 3) ^ ((arow >> 2) & 3);
  const unsigned short* srcA1 = xb + ((size_t)(rowbase + arow)) * K + aslot * 8;
  int ldsA1 = w * 512;

  auto STAGE = [&](int b, int t) {
    gll16(srcA1 + t * BK, ab + b * 2048 + ldsA1);
#pragma unroll
    for (int qq = 0; qq < 2; ++qq)
      gll16(srcB[qq] + (size_t)t * 8192, bl + b * 4096 + ldsB[qq]);
  };

  f32x4 zero4 = {0.f, 0.f, 0.f, 0.f};
  f32x4 acc[2][4];
#pragma unroll
  for (int m = 0; m < 2; ++m)
#pragma unroll
    for (int n = 0; n < 4; ++n) acc[m][n] = zero4;

  constexpr int NT = K / BK;
  STAGE(0, 0);
  __syncthreads();
  int buf = 0;
  for (int t = 0; t < NT; ++t) {
    if (t + 1 < NT) STAGE(buf ^ 1, t + 1);

    bf16x8 a[2], b[4];
#pragma unroll
    for (int m = 0; m < 2; ++m) {
      int row = wr * 32 + m * 16 + lr;
      a[m] = *(const bf16x8*)(ab + buf * 2048 + row * 32 +
                              ((lg ^ ((row >> 2) & 3)) << 3));
    }
#pragma unroll
    for (int n = 0; n < 4; ++n) {
      int row = wc * 64 + n * 16 + lr;
      b[n] = *(const bf16x8*)(bl + buf * 4096 + row * 32 +
                              ((lg ^ ((row >> 2) & 3)) << 3));
    }
#pragma unroll
    for (int m = 0; m < 2; ++m)
#pragma unroll
      for (int n = 0; n < 4; ++n)
        acc[m][n] = __builtin_amdgcn_mfma_f32_16x16x32_bf16(a[m], b[n], acc[m][n], 0, 0, 0);

    __syncthreads();
    buf ^= 1;
  }

#pragma unroll
  for (int m = 0; m < 2; ++m)
#pragma unroll
    for (int n = 0; n < 4; ++n)
#pragma unroll
      for (int rr = 0; rr < 4; ++rr) {
        float v = acc[m][n][rr] * scale;
        Hout[(size_t)(rowbase + wr * 32 + m * 16 + lg * 4 + rr) * HIDDEN +
             bn * 128 + wc * 64 + n * 16 + lr] = f2bf(silu_n(v));
      }
}

// ---- layer 4 + segment reduction ---------------------------------------
__global__ void k_l4(const unsigned short* __restrict__ H3, const unsigned short* __restrict__ W4t,
                     const int* __restrict__ perm, const int* __restrict__ species,
                     const int* __restrict__ sidx, const float* __restrict__ coeff,
                     float* __restrict__ out) {
  int w = threadIdx.x >> 6, l = threadIdx.x & 63;
  int row = blockIdx.x * 4 + w;
  int src = perm[row];
  if (src < 0) return;
  int sp = species[src];
  us4 h = *(const us4*)&H3[(size_t)row * HIDDEN + l * 4];
  us4 wv = *(const us4*)&W4t[sp * HIDDEN + l * 4];
  float sum = 0.f;
#pragma unroll
  for (int e = 0; e < 4; ++e) sum += bf2f(h[e]) * bf2f(wv[e]);
#pragma unroll
  for (int d = 32; d >= 1; d >>= 1) sum += __shfl_xor(sum, d, 64);
  if (l == 0)
    atomicAdd(&out[sidx[src]], sum * (0.0625f * 0.125f) + coeff[sp]);
}

// ---- launcher -----------------------------------------------------------
extern "C" void kernel_launch(void* const* d_in, const int* in_sizes, int n_in,
                              void* d_out, int out_size, void* d_ws, size_t ws_size,
                              hipStream_t stream) {
  const float* features = (const float*)d_in[0];
  const float* W1 = (const float*)d_in[1];
  const float* W2 = (const float*)d_in[2];
  const float* W3 = (const float*)d_in[3];
  const float* W4 = (const float*)d_in[4];
  const float* coeff = (const float*)d_in[5];
  const int* species = (const int*)d_in[6];
  const int* sidx = (const int*)d_in[7];
  float* out = (float*)d_out;

  char* ws = (char*)d_ws;
  int* ints = (int*)(ws + WS_INTS);
  const float* zs = (const float*)(ws + 128);       // zero-stub (16 B used)
  int* perm = (int*)(ws + WS_PERM);
  unsigned short* W1t = (unsigned short*)(ws + WS_W1T);
  unsigned short* W2t = (unsigned short*)(ws + WS_W2T);
  unsigned short* W3t = (unsigned short*)(ws + WS_W3T);
  unsigned short* W4t = (unsigned short*)(ws + WS_W4T);
  unsigned short* H1 = (unsigned short*)(ws + WS_H1);
  unsigned short* H2 = (unsigned short*)(ws + WS_H2);

  // species bucketing
  k_init<<<(MPAD + 255) / 256, 256, 0, stream>>>(ints, perm, out);
  k_count<<<NATOMS / 256, 256, 0, stream>>>(species, ints);
  k_offsets<<<1, 1, 0, stream>>>(ints);
  k_scatter<<<NATOMS / 256, 256, 0, stream>>>(species, ints, perm);

  // weight prep for layer 1 (W2/W3 tiled after L1 — they alias W1t)
  k_wtile<<<NSPEC * (NFEAT / 64) * (HIDDEN / 64), 256, 0, stream>>>(W1, W1t, NFEAT, HIDDEN);
  k_w4<<<NSPEC, 256, 0, stream>>>(W4, W4t);

  const float s1 = 1.f / sqrtf((float)NFEAT);
  const float s2 = 1.f / 16.f;

  // layer 1: BM=128 x BN=128, full K, 761 MB staged
  k_l1n<<<NBLK1, 512, 0, stream>>>(features, W1t, H1, perm, ints + 8, zs, s1);

  // W2/W3 prep (W1t region now dead)
  k_wtile<<<NSPEC * (HIDDEN / 64) * (HIDDEN / 64), 256, 0, stream>>>(W2, W2t, HIDDEN, HIDDEN);
  k_wtile<<<NSPEC * (HIDDEN / 64) * (HIDDEN / 64), 256, 0, stream>>>(W3, W3t, HIDDEN, HIDDEN);

  // layers 2, 3
  k_mlp2<<<NBLK2, 256, 0, stream>>>(H1, W2t, H2, ints + 8, s2);
  k_mlp2<<<NBLK2, 256, 0, stream>>>(H2, W3t, H1, ints + 8, s2);

  // layer 4 + segment sum + composition term
  k_l4<<<MPAD / 4, 256, 0, stream>>>(H1, W4t, perm, species, sidx, coeff, out);
}